// Round 12
// baseline (94.708 us; speedup 1.0000x reference)
//
#include <hip/hip_runtime.h>

// R11: within-probe phase ablation of the R7 ring kernel.
// template<V>: V0=stage-only, V1=stage+compute(no stores), V2=stores-only,
// V3=full (dispatched LAST -> correct d_out). asm-sinks prevent DCE (rule 17).
#define NG 8
#define PC 32
#define FC 64
#define HH 56
#define WW 56
#define CIN 256
#define COUT 512
#define NB 16
#define SL 66
#define PLANE (SL * 64)
#define NPL 5
#define HCH 7

typedef __bf16 bf16x8 __attribute__((ext_vector_type(8)));
typedef float f32x4 __attribute__((ext_vector_type(4)));

static __device__ __forceinline__ void lds_barrier() {
    asm volatile("s_waitcnt lgkmcnt(0)\n\ts_barrier" ::: "memory");
}

__global__ void cvt_w_kernel(const float* __restrict__ in,
                             __bf16* __restrict__ outb) {
    int id = blockIdx.x * blockDim.x + threadIdx.x;
    if (id >= NG * 9 * FC * PC) return;
    const int p = id & (PC - 1);
    int rest = id >> 5;
    const int f = rest & (FC - 1);
    rest >>= 6;
    const int t = rest % 9;
    const int g = rest / 9;
    outb[id] = (__bf16)in[(((size_t)(g * 9 + t)) * PC + p) * FC + f];
}

static __device__ __forceinline__ bf16x8 cvt8(f32x4 a, f32x4 b) {
    bf16x8 r;
    r[0] = (__bf16)a[0]; r[1] = (__bf16)a[1]; r[2] = (__bf16)a[2]; r[3] = (__bf16)a[3];
    r[4] = (__bf16)b[0]; r[5] = (__bf16)b[1]; r[6] = (__bf16)b[2]; r[7] = (__bf16)b[3];
    return r;
}

static __device__ __forceinline__ int swz(int loc) {
    return loc ^ (((loc >> 7) & 3) << 4);
}

template <int V>
__global__ __launch_bounds__(256, 4)
void ring_probe(const float* __restrict__ x,
                const __bf16* __restrict__ wb,
                const float* __restrict__ bias,
                float* __restrict__ out) {
    const int b   = blockIdx.x;
    const int g   = b & 7;
    const int hcb = (b >> 3) & 7;
    const int n   = b >> 6;
    const int h0  = hcb * HCH;

    const int tid  = threadIdx.x;
    const int wave = tid >> 6;
    const int lane = tid & 63;
    const int lo = lane & 15;
    const int hi = lane >> 4;
    const int p0 = hi * 8;
    const int fm  = (wave >> 1) * 32;
    const int wnb = (wave & 1) * 32;

    __shared__ __align__(16) unsigned char xsb[NPL * PLANE];

    constexpr bool DO_STAGE   = (V == 0 || V == 1 || V == 3);
    constexpr bool DO_COMPUTE = (V == 1 || V == 3);
    constexpr bool DO_STORE   = (V == 2 || V == 3);

    // weights only where compute runs
    bf16x8 bfr[9][2];
    if constexpr (DO_COMPUTE) {
        const __bf16* wgp = wb + ((size_t)g * 9 * FC) * PC;
#pragma unroll
        for (int t = 0; t < 9; ++t)
#pragma unroll
            for (int mi = 0; mi < 2; ++mi)
                bfr[t][mi] = *reinterpret_cast<const bf16x8*>(
                    wgp + ((size_t)t * FC + (fm + mi * 16 + lo)) * PC + p0);
    }

    if constexpr (DO_STAGE) {
        if (tid < 180) {
            const int q  = tid & 3;
            const int sq = tid >> 2;
            const int pl = sq / 9;
            const int s  = 57 + (sq % 9);
            *reinterpret_cast<bf16x8*>(xsb + pl * PLANE + swz(s * 64 + q * 16)) =
                (bf16x8)(__bf16)0.f;
        }
    }

    const int sq_q = tid & 3;
    const int sq_s = tid >> 2;
    const bool st_act = sq_s < 57;
    const int w_in = sq_s - 1;
    const bool w_ok = st_act && ((unsigned)w_in < WW);
    const float* xq = x + ((size_t)n * HH * WW) * CIN + g * PC + sq_q * 8;
    const int wloc = swz(sq_s * 64 + sq_q * 16);

    f32x4 sa = (f32x4)0.f, sb = (f32x4)0.f;
    if constexpr (DO_STAGE) {
        f32x4 pa[3], pb[3];
#pragma unroll
        for (int rr = 0; rr < 3; ++rr) {
            const int r = h0 - 1 + rr;
            pa[rr] = (f32x4)0.f; pb[rr] = (f32x4)0.f;
            if (w_ok && (unsigned)r < HH) {
                const float* p = xq + ((size_t)r * WW + w_in) * CIN;
                pa[rr] = *reinterpret_cast<const f32x4*>(p);
                pb[rr] = *reinterpret_cast<const f32x4*>(p + 4);
            }
        }
#pragma unroll
        for (int rr = 0; rr < 3; ++rr)
            if (st_act)
                *reinterpret_cast<bf16x8*>(xsb + rr * PLANE + wloc) = cvt8(pa[rr], pb[rr]);

        const int r = h0 + 2;
        if (w_ok && (unsigned)r < HH) {
            const float* p = xq + ((size_t)r * WW + w_in) * CIN;
            sa = *reinterpret_cast<const f32x4*>(p);
            sb = *reinterpret_cast<const f32x4*>(p + 4);
        }
    }

    float4 bvv[2];
#pragma unroll
    for (int mi = 0; mi < 2; ++mi)
        bvv[mi] = *reinterpret_cast<const float4*>(bias + g * FC + fm + mi * 16 + hi * 4);

    float* const outg = out + ((size_t)n * HH * WW) * COUT + g * FC;

#pragma unroll
    for (int i = 0; i < HCH; ++i) {
        const int h = h0 + i;

        if constexpr (DO_STAGE) {
            if (st_act)
                *reinterpret_cast<bf16x8*>(xsb + ((i + 3) % NPL) * PLANE + wloc) = cvt8(sa, sb);
            if (i + 1 < HCH) {
                const int r = h + 3;
                sa = (f32x4)0.f; sb = (f32x4)0.f;
                if (w_ok && (unsigned)r < HH) {
                    const float* p = xq + ((size_t)r * WW + w_in) * CIN;
                    sa = *reinterpret_cast<const f32x4*>(p);
                    sb = *reinterpret_cast<const f32x4*>(p + 4);
                }
            }
        }

        lds_barrier();

        if constexpr (V == 0) {
            // keep the ds_writes alive: one dependent ds_read, sunk
            bf16x8 v = *reinterpret_cast<const bf16x8*>(
                xsb + (i % NPL) * PLANE + wloc);
            asm volatile("" :: "v"(v));
        }

        f32x4 acc[2][2];
        if constexpr (DO_COMPUTE) {
#pragma unroll
            for (int mi = 0; mi < 2; ++mi)
#pragma unroll
                for (int nj = 0; nj < 2; ++nj) acc[mi][nj] = (f32x4)0.f;

#pragma unroll
            for (int kh = 0; kh < 3; ++kh) {
                const unsigned char* plb = xsb + ((i + kh) % NPL) * PLANE;
#pragma unroll
                for (int kw = 0; kw < 3; ++kw) {
                    const int t = kh * 3 + kw;
                    bf16x8 bx[2];
#pragma unroll
                    for (int nj = 0; nj < 2; ++nj) {
                        const int s = wnb + nj * 16 + lo + kw;
                        bx[nj] = *reinterpret_cast<const bf16x8*>(plb + swz(s * 64 + hi * 16));
                    }
#pragma unroll
                    for (int mi = 0; mi < 2; ++mi)
#pragma unroll
                        for (int nj = 0; nj < 2; ++nj)
                            acc[mi][nj] = __builtin_amdgcn_mfma_f32_16x16x32_bf16(
                                bfr[t][mi], bx[nj], acc[mi][nj], 0, 0, 0);
                }
            }
        }

        if constexpr (V == 1) {
#pragma unroll
            for (int mi = 0; mi < 2; ++mi)
#pragma unroll
                for (int nj = 0; nj < 2; ++nj)
                    asm volatile("" :: "v"(acc[mi][nj]));
        }

        if constexpr (DO_STORE) {
            float* const orow = outg + ((size_t)h * WW) * COUT;
#pragma unroll
            for (int mi = 0; mi < 2; ++mi) {
                const int f0 = fm + mi * 16 + hi * 4;
#pragma unroll
                for (int nj = 0; nj < 2; ++nj) {
                    const int w = wnb + nj * 16 + lo;
                    if (w < WW) {
                        f32x4 o;
                        if constexpr (V == 3) {
                            o = acc[mi][nj];
                            o[0] += bvv[mi].x; o[1] += bvv[mi].y;
                            o[2] += bvv[mi].z; o[3] += bvv[mi].w;
                        } else {
                            o[0] = bvv[mi].x; o[1] = bvv[mi].y;
                            o[2] = bvv[mi].z; o[3] = bvv[mi].w;
                        }
                        *reinterpret_cast<f32x4*>(orow + (size_t)w * COUT + f0) = o;
                    }
                }
            }
        }
    }
}

// ---------------- fallback fp32 kernel ----------------
__global__ __launch_bounds__(256, 2)
void groupconv_f32_kernel(const float* __restrict__ x,
                          const float* __restrict__ krn,
                          const float* __restrict__ bias,
                          float* __restrict__ out) {
    const int b  = blockIdx.x;
    const int g  = b % NG;
    const int h  = (b / NG) % HH;
    const int n  = b / (NG * HH);
    const int tid = threadIdx.x;
    const int f   = tid & 63;
    const int wq  = tid >> 6;
    const int wbase = wq * 14;

    float acc[14];
#pragma unroll
    for (int i = 0; i < 14; ++i) acc[i] = 0.f;

    const float* kg = krn + (size_t)g * (9 * PC * FC);

    for (int kh = 0; kh < 3; ++kh) {
        const int hin = h + kh - 1;
        if (hin < 0 || hin >= HH) continue;
        const float* xrow = x + (((size_t)n * HH + hin) * WW) * CIN + g * PC;
        for (int pq = 0; pq < 8; ++pq) {
            float4 xv[16];
#pragma unroll
            for (int t = 0; t < 16; ++t) {
                const int win = wbase + t - 1;
                if (win >= 0 && win < WW)
                    xv[t] = *reinterpret_cast<const float4*>(xrow + (size_t)win * CIN + pq * 4);
                else
                    xv[t] = make_float4(0.f, 0.f, 0.f, 0.f);
            }
#pragma unroll
            for (int kw = 0; kw < 3; ++kw) {
                const float* kp = kg + ((kh * 3 + kw) * PC + pq * 4) * FC + f;
                const float w0 = kp[0 * FC], w1 = kp[1 * FC], w2 = kp[2 * FC], w3 = kp[3 * FC];
#pragma unroll
                for (int i = 0; i < 14; ++i) {
                    const float4 xt = xv[i + kw];
                    acc[i] = fmaf(xt.x, w0, acc[i]);
                    acc[i] = fmaf(xt.y, w1, acc[i]);
                    acc[i] = fmaf(xt.z, w2, acc[i]);
                    acc[i] = fmaf(xt.w, w3, acc[i]);
                }
            }
        }
    }

    const float bv = bias[g * FC + f];
    float* orow = out + (((size_t)n * HH + h) * WW + wbase) * COUT + g * FC + f;
#pragma unroll
    for (int i = 0; i < 14; ++i) orow[(size_t)i * COUT] = acc[i] + bv;
}

// ---------------- launcher ----------------
extern "C" void kernel_launch(void* const* d_in, const int* in_sizes, int n_in,
                              void* d_out, int out_size, void* d_ws, size_t ws_size,
                              hipStream_t stream) {
    const float* x    = (const float*)d_in[0];
    const float* krn  = (const float*)d_in[1];
    const float* bias = (const float*)d_in[2];
    float* out = (float*)d_out;

    const size_t w_elems = (size_t)NG * 9 * FC * PC;
    if (ws_size < w_elems * sizeof(__bf16)) {
        groupconv_f32_kernel<<<NB * HH * NG, 256, 0, stream>>>(x, krn, bias, out);
        return;
    }

    __bf16* wbuf = (__bf16*)d_ws;
    cvt_w_kernel<<<(int)((w_elems + 255) / 256), 256, 0, stream>>>(krn, wbuf);

    const int blocks = NB * 8 * NG;  // 1024
    ring_probe<0><<<blocks, 256, 0, stream>>>(x, wbuf, bias, out);  // stage-only
    ring_probe<1><<<blocks, 256, 0, stream>>>(x, wbuf, bias, out);  // +compute
    ring_probe<2><<<blocks, 256, 0, stream>>>(x, wbuf, bias, out);  // stores-only
    ring_probe<3><<<blocks, 256, 0, stream>>>(x, wbuf, bias, out);  // full (last, correct)
}

// Round 13
// 46.165 us; speedup vs baseline: 2.0515x; 2.0515x over previous
//
#include <hip/hip_runtime.h>

// Grouped conv 3x3 SAME, NHWC fp32: bf16 pre-convert pass + MFMA conv with
// global_load_lds DMA staging into a 5-plane LDS ring, counted vmcnt(4)
// (stores in flight across barriers), verified R7 swizzle/compute/store.
#define NG 8
#define PC 32
#define FC 64
#define HH 56
#define WW 56
#define CIN 256
#define COUT 512
#define NB 16
#define SL 66
#define PLANE (SL * 64)    // 4224 B per plane
#define NPL 5
#define HCH 7

typedef __bf16 bf16x8 __attribute__((ext_vector_type(8)));
typedef float f32x4 __attribute__((ext_vector_type(4)));

static __device__ __forceinline__ void dma16(const void* gsrc, void* lds) {
    typedef const __attribute__((address_space(1))) unsigned int* gp_t;
    typedef __attribute__((address_space(3))) unsigned int* lp_t;
    __builtin_amdgcn_global_load_lds((gp_t)gsrc, (lp_t)lds, 16, 0, 0);
}

static __device__ __forceinline__ bf16x8 cvt8(f32x4 a, f32x4 b) {
    bf16x8 r;
    r[0] = (__bf16)a[0]; r[1] = (__bf16)a[1]; r[2] = (__bf16)a[2]; r[3] = (__bf16)a[3];
    r[4] = (__bf16)b[0]; r[5] = (__bf16)b[1]; r[6] = (__bf16)b[2]; r[7] = (__bf16)b[3];
    return r;
}

static __device__ __forceinline__ int swz(int loc) {
    return loc ^ (((loc >> 7) & 3) << 4);   // involution: bits4-5 ^= bits7-8
}

// ---- x f32 [n][h][w][g*32+c] -> bf16 [n][g][h][w][32c] (writes contiguous) ----
__global__ void cvt_x_kernel(const float* __restrict__ in,
                             __bf16* __restrict__ outb, int ntotal) {
    int id = blockIdx.x * blockDim.x + threadIdx.x;
    const int stride = gridDim.x * blockDim.x;
    for (; id < ntotal; id += stride) {
        const int qq = id & 3;
        int rest = id >> 2;                // (n*8+g)*56*56 + h*56 + w
        const int w = rest % WW;
        rest /= WW;
        const int h = rest % HH;
        const int ng = rest / HH;          // n*8+g
        const int g = ng & 7;
        const int n = ng >> 3;
        const float* p = in + (((size_t)n * HH + h) * WW + w) * CIN + g * PC + qq * 8;
        f32x4 a = *reinterpret_cast<const f32x4*>(p);
        f32x4 b = *reinterpret_cast<const f32x4*>(p + 4);
        *reinterpret_cast<bf16x8*>(outb + (size_t)id * 8) = cvt8(a, b);
    }
}

// kernels [g][kh][kw][p][f] f32 -> [g][tap][f][p] bf16
__global__ void cvt_w_kernel(const float* __restrict__ in,
                             __bf16* __restrict__ outb) {
    int id = blockIdx.x * blockDim.x + threadIdx.x;
    if (id >= NG * 9 * FC * PC) return;
    const int p = id & (PC - 1);
    int rest = id >> 5;
    const int f = rest & (FC - 1);
    rest >>= 6;
    const int t = rest % 9;
    const int g = rest / 9;
    outb[id] = (__bf16)in[(((size_t)(g * 9 + t)) * PC + p) * FC + f];
}

__global__ __launch_bounds__(256, 4)
void groupconv_dma_kernel(const __bf16* __restrict__ xb,
                          const __bf16* __restrict__ wb,
                          const float* __restrict__ bias,
                          float* __restrict__ out) {
    const int b   = blockIdx.x;
    const int g   = b & 7;
    const int hcb = (b >> 3) & 7;
    const int n   = b >> 6;
    const int h0  = hcb * HCH;

    const int tid  = threadIdx.x;
    const int wave = tid >> 6;
    const int lane = tid & 63;
    const int lo = lane & 15;
    const int hi = lane >> 4;
    const int p0 = hi * 8;
    const int fm  = (wave >> 1) * 32;
    const int wnb = (wave & 1) * 32;

    __shared__ __align__(16) unsigned char xsb[NPL * PLANE];  // 21120 B

    // stationary weight frags (A-operand: M=filters)
    bf16x8 bfr[9][2];
    {
        const __bf16* wgp = wb + ((size_t)g * 9 * FC) * PC;
#pragma unroll
        for (int t = 0; t < 9; ++t)
#pragma unroll
            for (int mi = 0; mi < 2; ++mi)
                bfr[t][mi] = *reinterpret_cast<const bf16x8*>(
                    wgp + ((size_t)t * FC + (fm + mi * 16 + lo)) * PC + p0);
    }

    // ---- DMA granule mapping: thread t owns LINEAR granule o=t*16 of a plane;
    //      its CONTENT is logical loc=swz(o) -> slot s, channel-octet qq.
    const int o   = tid * 16;
    const int loc = swz(o);
    const int s   = loc >> 6;
    const int qq  = (loc >> 4) & 3;
    const bool st_ok = (s >= 1 && s <= 56);      // slot 0 / 57+ are constant-zero
    const __bf16* xng = xb + (size_t)(n * 8 + g) * (HH * WW * PC);
    // per-lane global source for row r: xng + ((r*WW + (s-1))*PC + qq*8)

    // ---- one-time zero fill: masked granules of all planes; whole plane 0 if h0==0
#pragma unroll
    for (int pl = 0; pl < NPL; ++pl) {
        if (!st_ok || (pl == 0 && h0 == 0))
            *reinterpret_cast<bf16x8*>(xsb + pl * PLANE + o) = (bf16x8)(__bf16)0.f;
    }

    // ---- prologue DMAs: planes 0..2 <- rows h0-1..h0+1 ----
    {
        void* ldsw0 = xsb + 0 * PLANE + wave * 1024;
        void* ldsw1 = xsb + 1 * PLANE + wave * 1024;
        void* ldsw2 = xsb + 2 * PLANE + wave * 1024;
        if (h0 > 0 && st_ok)
            dma16(xng + ((size_t)(h0 - 1) * WW + (s - 1)) * PC + qq * 8, ldsw0);
        if (st_ok) {
            dma16(xng + ((size_t)(h0 + 0) * WW + (s - 1)) * PC + qq * 8, ldsw1);
            dma16(xng + ((size_t)(h0 + 1) * WW + (s - 1)) * PC + qq * 8, ldsw2);
        }
    }

    float4 bvv[2];
#pragma unroll
    for (int mi = 0; mi < 2; ++mi)
        bvv[mi] = *reinterpret_cast<const float4*>(bias + g * FC + fm + mi * 16 + hi * 4);

    float* const outg = out + ((size_t)n * HH * WW) * COUT + g * FC;

#pragma unroll
    for (int i = 0; i < HCH; ++i) {
        const int h = h0 + i;

        // sync: prologue (i==0) drains all DMAs; else counted vmcnt(4)
        // (4 = this wave's stores of iter i-1; DMA(i-1) is older -> complete).
        if (i == 0)
            asm volatile("s_waitcnt vmcnt(0) lgkmcnt(0)\n\ts_barrier" ::: "memory");
        else
            asm volatile("s_waitcnt vmcnt(4) lgkmcnt(0)\n\ts_barrier" ::: "memory");

        // issue DMA for row h+2 -> plane (i+3)%5 (read starting next iter)
        if (i < HCH - 1) {
            const int r = h + 2;
            void* ldsw = xsb + ((i + 3) % NPL) * PLANE + wave * 1024;
            if (r < HH) {
                if (st_ok)
                    dma16(xng + ((size_t)r * WW + (s - 1)) * PC + qq * 8, ldsw);
            } else {
                // OOB row: zero the active granules instead (uniform branch)
                if (st_ok)
                    *reinterpret_cast<bf16x8*>(xsb + ((i + 3) % NPL) * PLANE + o) =
                        (bf16x8)(__bf16)0.f;
            }
        }

        // compute row h: planes (i+kh)%5, 18 ds_read + 36 MFMA (verified R7 path)
        f32x4 acc[2][2];
#pragma unroll
        for (int mi = 0; mi < 2; ++mi)
#pragma unroll
            for (int nj = 0; nj < 2; ++nj) acc[mi][nj] = (f32x4)0.f;

#pragma unroll
        for (int kh = 0; kh < 3; ++kh) {
            const unsigned char* plb = xsb + ((i + kh) % NPL) * PLANE;
#pragma unroll
            for (int kw = 0; kw < 3; ++kw) {
                const int t = kh * 3 + kw;
                bf16x8 bx[2];
#pragma unroll
                for (int nj = 0; nj < 2; ++nj) {
                    const int ss = wnb + nj * 16 + lo + kw;
                    bx[nj] = *reinterpret_cast<const bf16x8*>(plb + swz(ss * 64 + hi * 16));
                }
#pragma unroll
                for (int mi = 0; mi < 2; ++mi)
#pragma unroll
                    for (int nj = 0; nj < 2; ++nj)
                        acc[mi][nj] = __builtin_amdgcn_mfma_f32_16x16x32_bf16(
                            bfr[t][mi], bx[nj], acc[mi][nj], 0, 0, 0);
            }
        }

        // store row h: exactly 4 store instructions per wave (vmcnt accounting)
        float* const orow = outg + ((size_t)h * WW) * COUT;
#pragma unroll
        for (int mi = 0; mi < 2; ++mi) {
            const int f0 = fm + mi * 16 + hi * 4;
#pragma unroll
            for (int nj = 0; nj < 2; ++nj) {
                const int w = wnb + nj * 16 + lo;
                if (w < WW) {
                    f32x4 oo = acc[mi][nj];
                    oo[0] += bvv[mi].x; oo[1] += bvv[mi].y;
                    oo[2] += bvv[mi].z; oo[3] += bvv[mi].w;
                    *reinterpret_cast<f32x4*>(orow + (size_t)w * COUT + f0) = oo;
                }
            }
        }
    }
}

// ---------------- fallback fp32 kernel ----------------
__global__ __launch_bounds__(256, 2)
void groupconv_f32_kernel(const float* __restrict__ x,
                          const float* __restrict__ krn,
                          const float* __restrict__ bias,
                          float* __restrict__ out) {
    const int b  = blockIdx.x;
    const int g  = b % NG;
    const int h  = (b / NG) % HH;
    const int n  = b / (NG * HH);
    const int tid = threadIdx.x;
    const int f   = tid & 63;
    const int wq  = tid >> 6;
    const int wbase = wq * 14;

    float acc[14];
#pragma unroll
    for (int i = 0; i < 14; ++i) acc[i] = 0.f;

    const float* kg = krn + (size_t)g * (9 * PC * FC);

    for (int kh = 0; kh < 3; ++kh) {
        const int hin = h + kh - 1;
        if (hin < 0 || hin >= HH) continue;
        const float* xrow = x + (((size_t)n * HH + hin) * WW) * CIN + g * PC;
        for (int pq = 0; pq < 8; ++pq) {
            float4 xv[16];
#pragma unroll
            for (int t = 0; t < 16; ++t) {
                const int win = wbase + t - 1;
                if (win >= 0 && win < WW)
                    xv[t] = *reinterpret_cast<const float4*>(xrow + (size_t)win * CIN + pq * 4);
                else
                    xv[t] = make_float4(0.f, 0.f, 0.f, 0.f);
            }
#pragma unroll
            for (int kw = 0; kw < 3; ++kw) {
                const float* kp = kg + ((kh * 3 + kw) * PC + pq * 4) * FC + f;
                const float w0 = kp[0 * FC], w1 = kp[1 * FC], w2 = kp[2 * FC], w3 = kp[3 * FC];
#pragma unroll
                for (int i = 0; i < 14; ++i) {
                    const float4 xt = xv[i + kw];
                    acc[i] = fmaf(xt.x, w0, acc[i]);
                    acc[i] = fmaf(xt.y, w1, acc[i]);
                    acc[i] = fmaf(xt.z, w2, acc[i]);
                    acc[i] = fmaf(xt.w, w3, acc[i]);
                }
            }
        }
    }

    const float bv = bias[g * FC + f];
    float* orow = out + (((size_t)n * HH + h) * WW + wbase) * COUT + g * FC + f;
#pragma unroll
    for (int i = 0; i < 14; ++i) orow[(size_t)i * COUT] = acc[i] + bv;
}

// ---------------- launcher ----------------
extern "C" void kernel_launch(void* const* d_in, const int* in_sizes, int n_in,
                              void* d_out, int out_size, void* d_ws, size_t ws_size,
                              hipStream_t stream) {
    const float* x    = (const float*)d_in[0];
    const float* krn  = (const float*)d_in[1];
    const float* bias = (const float*)d_in[2];
    float* out = (float*)d_out;

    const size_t x_elems = (size_t)NB * NG * HH * WW * PC;   // 12,845,056
    const size_t w_elems = (size_t)NG * 9 * FC * PC;         // 147,456
    const size_t need = (x_elems + w_elems) * sizeof(__bf16);

    if (ws_size < need) {
        groupconv_f32_kernel<<<NB * HH * NG, 256, 0, stream>>>(x, krn, bias, out);
        return;
    }

    __bf16* xbuf = (__bf16*)d_ws;
    __bf16* wbuf = xbuf + x_elems;

    const int ngran = (int)(x_elems / 8);                    // 1,605,632
    cvt_x_kernel<<<2048, 256, 0, stream>>>(x, xbuf, ngran);
    cvt_w_kernel<<<(int)((w_elems + 255) / 256), 256, 0, stream>>>(krn, wbuf);

    const int blocks = NB * 8 * NG;                          // 1024
    groupconv_dma_kernel<<<blocks, 256, 0, stream>>>(xbuf, wbuf, bias, out);
}

// Round 15
// 45.401 us; speedup vs baseline: 2.0860x; 1.0168x over previous
//
#include <hip/hip_runtime.h>

// Grouped conv 3x3 SAME, NHWC fp32 -> bf16 MFMA.
// R14 = R13 + fix: paired swizzled LDS read's second 16B is at lin^16 (not
// lin+16) — linear = swz32(logical), and swz32(loc+16) = swz32(loc)^16.
#define NG 8
#define PC 32
#define FC 64
#define HH 56
#define WW 56
#define CIN 256
#define COUT 512
#define NB 16
#define SL2 64               // w slots (f32): w_in = slot-1 in [-1,62]; 57..63 zero
#define PL32 (SL2 * 128)     // 8192 B per plane (64 slots * 32ch * 4B)
#define NPL 4                // ring planes (32768 B total)
#define HCH 7

typedef __bf16 bf16x8 __attribute__((ext_vector_type(8)));
typedef float f32x4 __attribute__((ext_vector_type(4)));

static __device__ __forceinline__ void dma16(const void* gsrc, void* lds) {
    typedef const __attribute__((address_space(1))) unsigned int* gp_t;
    typedef __attribute__((address_space(3))) unsigned int* lp_t;
    __builtin_amdgcn_global_load_lds((gp_t)gsrc, (lp_t)lds, 16, 0, 0);
}

static __device__ __forceinline__ bf16x8 cvt8(f32x4 a, f32x4 b) {
    bf16x8 r;
    r[0] = (__bf16)a[0]; r[1] = (__bf16)a[1]; r[2] = (__bf16)a[2]; r[3] = (__bf16)a[3];
    r[4] = (__bf16)b[0]; r[5] = (__bf16)b[1]; r[6] = (__bf16)b[2]; r[7] = (__bf16)b[3];
    return r;
}

// f32-plane swizzle: XOR slot low bits into the 16B-granule index (involution)
static __device__ __forceinline__ int swz32(int loc) {
    return loc ^ (((loc >> 7) & 7) << 4);
}

// kernels [g][kh][kw][p][f] f32 -> [g][tap][f][p] bf16
__global__ void cvt_w_kernel(const float* __restrict__ in,
                             __bf16* __restrict__ outb) {
    int id = blockIdx.x * blockDim.x + threadIdx.x;
    if (id >= NG * 9 * FC * PC) return;
    const int p = id & (PC - 1);
    int rest = id >> 5;
    const int f = rest & (FC - 1);
    rest >>= 6;
    const int t = rest % 9;
    const int g = rest / 9;
    outb[id] = (__bf16)in[(((size_t)(g * 9 + t)) * PC + p) * FC + f];
}

__global__ __launch_bounds__(256, 4)
void groupconv_f32dma_kernel(const float* __restrict__ x,
                             const __bf16* __restrict__ wb,
                             const float* __restrict__ bias,
                             float* __restrict__ out) {
    const int b   = blockIdx.x;
    const int g   = b & 7;
    const int hcb = (b >> 3) & 7;
    const int n   = b >> 6;
    const int h0  = hcb * HCH;

    const int tid  = threadIdx.x;
    const int wave = tid >> 6;
    const int lane = tid & 63;
    const int lo = lane & 15;
    const int hi = lane >> 4;
    const int p0 = hi * 8;
    const int fm  = (wave >> 1) * 32;
    const int wnb = (wave & 1) * 32;

    __shared__ __align__(16) unsigned char xsb[NPL * PL32];  // 32768 B

    // stationary weight frags (A-operand: M=filters)
    bf16x8 bfr[9][2];
    {
        const __bf16* wgp = wb + ((size_t)g * 9 * FC) * PC;
#pragma unroll
        for (int t = 0; t < 9; ++t)
#pragma unroll
            for (int mi = 0; mi < 2; ++mi)
                bfr[t][mi] = *reinterpret_cast<const bf16x8*>(
                    wgp + ((size_t)t * FC + (fm + mi * 16 + lo)) * PC + p0);
    }

    // ---- DMA granule mapping: 512 granules/plane; thread owns j0=tid, j1=tid+256.
    // Linear granule o=j*16 holds logical loc=swz32(o): slot s=loc>>7, quad q=(loc>>4)&7.
    const int o0 = tid * 16,        o1 = (tid + 256) * 16;
    const int l0 = swz32(o0),       l1 = swz32(o1);
    const int s0 = l0 >> 7,         s1 = l1 >> 7;
    const int q0 = (l0 >> 4) & 7,   q1 = (l1 >> 4) & 7;
    const bool ok0 = (s0 >= 1 && s0 <= 56);
    const bool ok1 = (s1 >= 1 && s1 <= 56);
    const float* xg = x + ((size_t)n * HH * WW) * CIN + g * PC;
    const size_t off0 = (size_t)(s0 - 1) * CIN + q0 * 4;   // + r*WW*CIN
    const size_t off1 = (size_t)(s1 - 1) * CIN + q1 * 4;

    // ---- one-time zero fill: invalid granules of all planes; plane 0 if h0==0
#pragma unroll
    for (int pl = 0; pl < NPL; ++pl) {
        unsigned char* plb = xsb + pl * PL32;
        if (!ok0 || (pl == 0 && h0 == 0))
            *reinterpret_cast<f32x4*>(plb + o0) = (f32x4)0.f;
        if (!ok1 || (pl == 0 && h0 == 0))
            *reinterpret_cast<f32x4*>(plb + o1) = (f32x4)0.f;
    }

    // ---- prologue DMAs: planes 0..2 <- rows h0-1..h0+1 ----
#pragma unroll
    for (int rr = 0; rr < 3; ++rr) {
        const int r = h0 - 1 + rr;
        if (r >= 0) {   // r<56 guaranteed here
            const float* rowp = xg + (size_t)r * WW * CIN;
            void* d0 = xsb + rr * PL32 + wave * 1024;
            void* d1 = xsb + rr * PL32 + 4096 + wave * 1024;
            if (ok0) dma16(rowp + off0, d0);
            if (ok1) dma16(rowp + off1, d1);
        }
    }

    float4 bvv[2];
#pragma unroll
    for (int mi = 0; mi < 2; ++mi)
        bvv[mi] = *reinterpret_cast<const float4*>(bias + g * FC + fm + mi * 16 + hi * 4);

    float* const outg = out + ((size_t)n * HH * WW) * COUT + g * FC;

#pragma unroll
    for (int i = 0; i < HCH; ++i) {
        const int h = h0 + i;

        // sync: i==0 drains prologue; else counted vmcnt(4) (4 = last iter's stores;
        // DMA(i-1) pair is older -> complete; stores stay in flight).
        if (i == 0)
            asm volatile("s_waitcnt vmcnt(0) lgkmcnt(0)\n\ts_barrier" ::: "memory");
        else
            asm volatile("s_waitcnt vmcnt(4) lgkmcnt(0)\n\ts_barrier" ::: "memory");

        // stage row h+2 -> plane (i+3)%4
        if (i < HCH - 1) {
            const int r = h + 2;
            unsigned char* plb = xsb + ((i + 3) % NPL) * PL32;
            if (r < HH) {
                const float* rowp = xg + (size_t)r * WW * CIN;
                if (ok0) dma16(rowp + off0, plb + (size_t)wave * 1024);
                if (ok1) dma16(rowp + off1, plb + 4096 + (size_t)wave * 1024);
            } else {
                if (ok0) *reinterpret_cast<f32x4*>(plb + o0) = (f32x4)0.f;
                if (ok1) *reinterpret_cast<f32x4*>(plb + o1) = (f32x4)0.f;
            }
        }

        // compute row h: planes (i+kh)%4; paired swizzled reads + cvt + 36 MFMA
        f32x4 acc[2][2];
#pragma unroll
        for (int mi = 0; mi < 2; ++mi)
#pragma unroll
            for (int nj = 0; nj < 2; ++nj) acc[mi][nj] = (f32x4)0.f;

#pragma unroll
        for (int kh = 0; kh < 3; ++kh) {
            const unsigned char* plb = xsb + ((i + kh) % NPL) * PL32;
#pragma unroll
            for (int kw = 0; kw < 3; ++kw) {
                const int t = kh * 3 + kw;
                bf16x8 bx[2];
#pragma unroll
                for (int nj = 0; nj < 2; ++nj) {
                    int ss = wnb + nj * 16 + lo + kw;
                    ss = (ss > 63) ? 63 : ss;            // clamped cols are discarded
                    const int lin = swz32(ss * 128 + hi * 32);
                    f32x4 a  = *reinterpret_cast<const f32x4*>(plb + lin);
                    f32x4 b2 = *reinterpret_cast<const f32x4*>(plb + (lin ^ 16));  // FIX
                    bx[nj] = cvt8(a, b2);
                }
#pragma unroll
                for (int mi = 0; mi < 2; ++mi)
#pragma unroll
                    for (int nj = 0; nj < 2; ++nj)
                        acc[mi][nj] = __builtin_amdgcn_mfma_f32_16x16x32_bf16(
                            bfr[t][mi], bx[nj], acc[mi][nj], 0, 0, 0);
            }
        }

        // store row h: exactly 4 store instructions per wave (vmcnt accounting)
        float* const orow = outg + ((size_t)h * WW) * COUT;
#pragma unroll
        for (int mi = 0; mi < 2; ++mi) {
            const int f0 = fm + mi * 16 + hi * 4;
#pragma unroll
            for (int nj = 0; nj < 2; ++nj) {
                const int w = wnb + nj * 16 + lo;
                if (w < WW) {
                    f32x4 oo = acc[mi][nj];
                    oo[0] += bvv[mi].x; oo[1] += bvv[mi].y;
                    oo[2] += bvv[mi].z; oo[3] += bvv[mi].w;
                    *reinterpret_cast<f32x4*>(orow + (size_t)w * COUT + f0) = oo;
                }
            }
        }
    }
}

// ---------------- fallback fp32 kernel ----------------
__global__ __launch_bounds__(256, 2)
void groupconv_f32_kernel(const float* __restrict__ x,
                          const float* __restrict__ krn,
                          const float* __restrict__ bias,
                          float* __restrict__ out) {
    const int b  = blockIdx.x;
    const int g  = b % NG;
    const int h  = (b / NG) % HH;
    const int n  = b / (NG * HH);
    const int tid = threadIdx.x;
    const int f   = tid & 63;
    const int wq  = tid >> 6;
    const int wbase = wq * 14;

    float acc[14];
#pragma unroll
    for (int i = 0; i < 14; ++i) acc[i] = 0.f;

    const float* kg = krn + (size_t)g * (9 * PC * FC);

    for (int kh = 0; kh < 3; ++kh) {
        const int hin = h + kh - 1;
        if (hin < 0 || hin >= HH) continue;
        const float* xrow = x + (((size_t)n * HH + hin) * WW) * CIN + g * PC;
        for (int pq = 0; pq < 8; ++pq) {
            float4 xv[16];
#pragma unroll
            for (int t = 0; t < 16; ++t) {
                const int win = wbase + t - 1;
                if (win >= 0 && win < WW)
                    xv[t] = *reinterpret_cast<const float4*>(xrow + (size_t)win * CIN + pq * 4);
                else
                    xv[t] = make_float4(0.f, 0.f, 0.f, 0.f);
            }
#pragma unroll
            for (int kw = 0; kw < 3; ++kw) {
                const float* kp = kg + ((kh * 3 + kw) * PC + pq * 4) * FC + f;
                const float w0 = kp[0 * FC], w1 = kp[1 * FC], w2 = kp[2 * FC], w3 = kp[3 * FC];
#pragma unroll
                for (int i = 0; i < 14; ++i) {
                    const float4 xt = xv[i + kw];
                    acc[i] = fmaf(xt.x, w0, acc[i]);
                    acc[i] = fmaf(xt.y, w1, acc[i]);
                    acc[i] = fmaf(xt.z, w2, acc[i]);
                    acc[i] = fmaf(xt.w, w3, acc[i]);
                }
            }
        }
    }

    const float bv = bias[g * FC + f];
    float* orow = out + (((size_t)n * HH + h) * WW + wbase) * COUT + g * FC + f;
#pragma unroll
    for (int i = 0; i < 14; ++i) orow[(size_t)i * COUT] = acc[i] + bv;
}

// ---------------- launcher ----------------
extern "C" void kernel_launch(void* const* d_in, const int* in_sizes, int n_in,
                              void* d_out, int out_size, void* d_ws, size_t ws_size,
                              hipStream_t stream) {
    const float* x    = (const float*)d_in[0];
    const float* krn  = (const float*)d_in[1];
    const float* bias = (const float*)d_in[2];
    float* out = (float*)d_out;

    const size_t w_elems = (size_t)NG * 9 * FC * PC;
    if (ws_size < w_elems * sizeof(__bf16)) {
        groupconv_f32_kernel<<<NB * HH * NG, 256, 0, stream>>>(x, krn, bias, out);
        return;
    }

    __bf16* wbuf = (__bf16*)d_ws;
    cvt_w_kernel<<<(int)((w_elems + 255) / 256), 256, 0, stream>>>(krn, wbuf);

    const int blocks = NB * 8 * NG;  // 1024
    groupconv_f32dma_kernel<<<blocks, 256, 0, stream>>>(x, wbuf, bias, out);
}

// Round 16
// 41.400 us; speedup vs baseline: 2.2876x; 1.0967x over previous
//
#include <hip/hip_runtime.h>

// Grouped conv 3x3 SAME, NHWC fp32 -> bf16 MFMA.
// R15: DMA raw f32 rows into 2 per-wave-private LDS F-planes (global_load_lds,
// linear dest + inverse-swz32 source), convert f32->bf16 on-chip into the
// verified R7 bf16 5-plane ring, compute = R7's low-conflict bf16 path.
// One vmcnt(4)+lgkmcnt(0)+barrier per iter; stores stay in flight.
#define NG 8
#define PC 32
#define FC 64
#define HH 56
#define WW 56
#define CIN 256
#define COUT 512
#define NB 16
#define SL 66                 // bf16 w slots: w_in = slot-1 in [-1,64]
#define PLANE (SL * 64)       // 4224 B per bf16 plane
#define NPL 5                 // bf16 ring planes
#define PLF (64 * 128)        // 8192 B per f32 plane (64 slots x 32ch x 4B)
#define HCH 7

typedef __bf16 bf16x8 __attribute__((ext_vector_type(8)));
typedef float f32x4 __attribute__((ext_vector_type(4)));

static __device__ __forceinline__ void dma16(const void* gsrc, void* lds) {
    typedef const __attribute__((address_space(1))) unsigned int* gp_t;
    typedef __attribute__((address_space(3))) unsigned int* lp_t;
    __builtin_amdgcn_global_load_lds((gp_t)gsrc, (lp_t)lds, 16, 0, 0);
}

static __device__ __forceinline__ bf16x8 cvt8(f32x4 a, f32x4 b) {
    bf16x8 r;
    r[0] = (__bf16)a[0]; r[1] = (__bf16)a[1]; r[2] = (__bf16)a[2]; r[3] = (__bf16)a[3];
    r[4] = (__bf16)b[0]; r[5] = (__bf16)b[1]; r[6] = (__bf16)b[2]; r[7] = (__bf16)b[3];
    return r;
}

static __device__ __forceinline__ int swz(int loc) {       // bf16 plane (R7)
    return loc ^ (((loc >> 7) & 3) << 4);
}
static __device__ __forceinline__ int swz32(int loc) {     // f32 plane
    return loc ^ (((loc >> 7) & 7) << 4);
}

// kernels [g][kh][kw][p][f] f32 -> [g][tap][f][p] bf16
__global__ void cvt_w_kernel(const float* __restrict__ in,
                             __bf16* __restrict__ outb) {
    int id = blockIdx.x * blockDim.x + threadIdx.x;
    if (id >= NG * 9 * FC * PC) return;
    const int p = id & (PC - 1);
    int rest = id >> 5;
    const int f = rest & (FC - 1);
    rest >>= 6;
    const int t = rest % 9;
    const int g = rest / 9;
    outb[id] = (__bf16)in[(((size_t)(g * 9 + t)) * PC + p) * FC + f];
}

__global__ __launch_bounds__(256, 4)
void groupconv_dcv_kernel(const float* __restrict__ x,
                          const __bf16* __restrict__ wb,
                          const float* __restrict__ bias,
                          float* __restrict__ out) {
    const int b   = blockIdx.x;
    const int g   = b & 7;
    const int hcb = (b >> 3) & 7;
    const int n   = b >> 6;
    const int h0  = hcb * HCH;

    const int tid  = threadIdx.x;
    const int wave = tid >> 6;
    const int lane = tid & 63;
    const int lo = lane & 15;
    const int hi = lane >> 4;
    const int p0 = hi * 8;
    const int fm  = (wave >> 1) * 32;
    const int wnb = (wave & 1) * 32;

    __shared__ __align__(16) unsigned char lds[2 * PLF + NPL * PLANE];  // 37504 B
    unsigned char* const F0 = lds;
    unsigned char* const F1 = lds + PLF;
    unsigned char* const Bb = lds + 2 * PLF;

    // stationary weight frags (A-operand: M=filters)
    bf16x8 bfr[9][2];
    {
        const __bf16* wgp = wb + ((size_t)g * 9 * FC) * PC;
#pragma unroll
        for (int t = 0; t < 9; ++t)
#pragma unroll
            for (int mi = 0; mi < 2; ++mi)
                bfr[t][mi] = *reinterpret_cast<const bf16x8*>(
                    wgp + ((size_t)t * FC + (fm + mi * 16 + lo)) * PC + p0);
    }

    // ---- DMA granule mapping (f32 planes): linear o holds logical swz32(o) ----
    const int o0 = tid * 16,        o1 = (tid + 256) * 16;
    const int l0 = swz32(o0),       l1 = swz32(o1);
    const int s0 = l0 >> 7,         s1 = l1 >> 7;
    const int q0 = (l0 >> 4) & 7,   q1 = (l1 >> 4) & 7;
    const bool ok0 = (s0 >= 1 && s0 <= 56);
    const bool ok1 = (s1 >= 1 && s1 <= 56);
    const float* xg = x + ((size_t)n * HH * WW) * CIN + g * PC;
    const size_t off0 = (size_t)(s0 - 1) * CIN + q0 * 4;   // + r*WW*CIN
    const size_t off1 = (size_t)(s1 - 1) * CIN + q1 * 4;

    // ---- cvt mapping: thread -> bf16 granule (slot sc, octet qc) ----
    const int sc  = tid >> 2;          // 0..63
    const int qc  = tid & 3;
    const int frd = swz32(sc * 128 + qc * 32);     // f32 lo-quad read addr
    const int bwr = swz(sc * 64 + qc * 16);        // bf16 write addr

    // ---- one-time zeros: invalid F granules (both planes); B slots 57..65 ----
    if (!ok0) { *reinterpret_cast<f32x4*>(F0 + o0) = (f32x4)0.f;
                *reinterpret_cast<f32x4*>(F1 + o0) = (f32x4)0.f; }
    if (!ok1) { *reinterpret_cast<f32x4*>(F0 + o1) = (f32x4)0.f;
                *reinterpret_cast<f32x4*>(F1 + o1) = (f32x4)0.f; }
    if (tid < 180) {
        const int q  = tid & 3;
        const int sq = tid >> 2;        // 0..44
        const int pl = sq / 9;
        const int s  = 57 + (sq % 9);
        *reinterpret_cast<bf16x8*>(Bb + pl * PLANE + swz(s * 64 + q * 16)) =
            (bf16x8)(__bf16)0.f;
    }

#define STAGE(r_, Fdst)                                                         \
    do {                                                                        \
        const int r__ = (r_);                                                   \
        if ((unsigned)r__ < HH) {                                               \
            const float* rowp__ = xg + (size_t)r__ * WW * CIN;                  \
            if (ok0) dma16(rowp__ + off0, (Fdst) + wave * 1024);                \
            if (ok1) dma16(rowp__ + off1, (Fdst) + 4096 + wave * 1024);         \
        } else {                                                                \
            if (ok0) *reinterpret_cast<f32x4*>((Fdst) + o0) = (f32x4)0.f;       \
            if (ok1) *reinterpret_cast<f32x4*>((Fdst) + o1) = (f32x4)0.f;       \
        }                                                                       \
    } while (0)

#define CVTROW(Fsrc, Bdst)                                                      \
    do {                                                                        \
        f32x4 a__  = *reinterpret_cast<const f32x4*>((Fsrc) + frd);             \
        f32x4 b2__ = *reinterpret_cast<const f32x4*>((Fsrc) + (frd ^ 16));      \
        *reinterpret_cast<bf16x8*>((Bdst) + bwr) = cvt8(a__, b2__);             \
    } while (0)

    // ---- prologue: build B[0..2] = rows h0-1..h0+1; leave F0 = row h0+2 ----
    STAGE(h0 - 1, F0);
    STAGE(h0,     F1);
    asm volatile("s_waitcnt vmcnt(0) lgkmcnt(0)\n\ts_barrier" ::: "memory");
    CVTROW(F0, Bb + 0 * PLANE);
    CVTROW(F1, Bb + 1 * PLANE);
    asm volatile("s_waitcnt lgkmcnt(0)\n\ts_barrier" ::: "memory");
    STAGE(h0 + 1, F0);
    asm volatile("s_waitcnt vmcnt(0) lgkmcnt(0)\n\ts_barrier" ::: "memory");
    CVTROW(F0, Bb + 2 * PLANE);
    asm volatile("s_waitcnt lgkmcnt(0)\n\ts_barrier" ::: "memory");
    STAGE(h0 + 2, F0);

    float4 bvv[2];
#pragma unroll
    for (int mi = 0; mi < 2; ++mi)
        bvv[mi] = *reinterpret_cast<const float4*>(bias + g * FC + fm + mi * 16 + hi * 4);

    float* const outg = out + ((size_t)n * HH * WW) * COUT + g * FC;

#pragma unroll
    for (int i = 0; i < HCH; ++i) {
        const int h = h0 + i;

        // one barrier/iter: i==0 drains prologue DMA; else vmcnt(4) = last
        // iter's 4 stores (newest) -> DMA(i-1) complete; stores stay in flight.
        if (i == 0)
            asm volatile("s_waitcnt vmcnt(0) lgkmcnt(0)\n\ts_barrier" ::: "memory");
        else
            asm volatile("s_waitcnt vmcnt(4) lgkmcnt(0)\n\ts_barrier" ::: "memory");

        // cvt row h+2 (F[i&1]) -> bf16 plane (i+3)%5
        if (i <= HCH - 2) {
            const unsigned char* Fsrc = (i & 1) ? F1 : F0;
            CVTROW(Fsrc, Bb + ((i + 3) % NPL) * PLANE);
        }
        // DMA row h+3 -> F[(i+1)&1] (consumed by cvt at iter i+1)
        if (i <= HCH - 3) {
            unsigned char* Fdst = ((i + 1) & 1) ? F1 : F0;
            STAGE(h + 3, Fdst);
        }

        // compute row h: planes (i+kh)%5, 18 ds_read + 36 MFMA (R7-verified)
        f32x4 acc[2][2];
#pragma unroll
        for (int mi = 0; mi < 2; ++mi)
#pragma unroll
            for (int nj = 0; nj < 2; ++nj) acc[mi][nj] = (f32x4)0.f;

#pragma unroll
        for (int kh = 0; kh < 3; ++kh) {
            const unsigned char* plb = Bb + ((i + kh) % NPL) * PLANE;
#pragma unroll
            for (int kw = 0; kw < 3; ++kw) {
                const int t = kh * 3 + kw;
                bf16x8 bx[2];
#pragma unroll
                for (int nj = 0; nj < 2; ++nj) {
                    const int ss = wnb + nj * 16 + lo + kw;
                    bx[nj] = *reinterpret_cast<const bf16x8*>(plb + swz(ss * 64 + hi * 16));
                }
#pragma unroll
                for (int mi = 0; mi < 2; ++mi)
#pragma unroll
                    for (int nj = 0; nj < 2; ++nj)
                        acc[mi][nj] = __builtin_amdgcn_mfma_f32_16x16x32_bf16(
                            bfr[t][mi], bx[nj], acc[mi][nj], 0, 0, 0);
            }
        }

        // store row h: exactly 4 store instructions per wave (vmcnt accounting)
        float* const orow = outg + ((size_t)h * WW) * COUT;
#pragma unroll
        for (int mi = 0; mi < 2; ++mi) {
            const int f0 = fm + mi * 16 + hi * 4;
#pragma unroll
            for (int nj = 0; nj < 2; ++nj) {
                const int w = wnb + nj * 16 + lo;
                if (w < WW) {
                    f32x4 oo = acc[mi][nj];
                    oo[0] += bvv[mi].x; oo[1] += bvv[mi].y;
                    oo[2] += bvv[mi].z; oo[3] += bvv[mi].w;
                    *reinterpret_cast<f32x4*>(orow + (size_t)w * COUT + f0) = oo;
                }
            }
        }
    }
#undef STAGE
#undef CVTROW
}

// ---------------- fallback fp32 kernel ----------------
__global__ __launch_bounds__(256, 2)
void groupconv_f32_kernel(const float* __restrict__ x,
                          const float* __restrict__ krn,
                          const float* __restrict__ bias,
                          float* __restrict__ out) {
    const int b  = blockIdx.x;
    const int g  = b % NG;
    const int h  = (b / NG) % HH;
    const int n  = b / (NG * HH);
    const int tid = threadIdx.x;
    const int f   = tid & 63;
    const int wq  = tid >> 6;
    const int wbase = wq * 14;

    float acc[14];
#pragma unroll
    for (int i = 0; i < 14; ++i) acc[i] = 0.f;

    const float* kg = krn + (size_t)g * (9 * PC * FC);

    for (int kh = 0; kh < 3; ++kh) {
        const int hin = h + kh - 1;
        if (hin < 0 || hin >= HH) continue;
        const float* xrow = x + (((size_t)n * HH + hin) * WW) * CIN + g * PC;
        for (int pq = 0; pq < 8; ++pq) {
            float4 xv[16];
#pragma unroll
            for (int t = 0; t < 16; ++t) {
                const int win = wbase + t - 1;
                if (win >= 0 && win < WW)
                    xv[t] = *reinterpret_cast<const float4*>(xrow + (size_t)win * CIN + pq * 4);
                else
                    xv[t] = make_float4(0.f, 0.f, 0.f, 0.f);
            }
#pragma unroll
            for (int kw = 0; kw < 3; ++kw) {
                const float* kp = kg + ((kh * 3 + kw) * PC + pq * 4) * FC + f;
                const float w0 = kp[0 * FC], w1 = kp[1 * FC], w2 = kp[2 * FC], w3 = kp[3 * FC];
#pragma unroll
                for (int i = 0; i < 14; ++i) {
                    const float4 xt = xv[i + kw];
                    acc[i] = fmaf(xt.x, w0, acc[i]);
                    acc[i] = fmaf(xt.y, w1, acc[i]);
                    acc[i] = fmaf(xt.z, w2, acc[i]);
                    acc[i] = fmaf(xt.w, w3, acc[i]);
                }
            }
        }
    }

    const float bv = bias[g * FC + f];
    float* orow = out + (((size_t)n * HH + h) * WW + wbase) * COUT + g * FC + f;
#pragma unroll
    for (int i = 0; i < 14; ++i) orow[(size_t)i * COUT] = acc[i] + bv;
}

// ---------------- launcher ----------------
extern "C" void kernel_launch(void* const* d_in, const int* in_sizes, int n_in,
                              void* d_out, int out_size, void* d_ws, size_t ws_size,
                              hipStream_t stream) {
    const float* x    = (const float*)d_in[0];
    const float* krn  = (const float*)d_in[1];
    const float* bias = (const float*)d_in[2];
    float* out = (float*)d_out;

    const size_t w_elems = (size_t)NG * 9 * FC * PC;
    if (ws_size < w_elems * sizeof(__bf16)) {
        groupconv_f32_kernel<<<NB * HH * NG, 256, 0, stream>>>(x, krn, bias, out);
        return;
    }

    __bf16* wbuf = (__bf16*)d_ws;
    cvt_w_kernel<<<(int)((w_elems + 255) / 256), 256, 0, stream>>>(krn, wbuf);

    const int blocks = NB * 8 * NG;  // 1024
    groupconv_dcv_kernel<<<blocks, 256, 0, stream>>>(x, wbuf, bias, out);
}